// Round 7
// baseline (575.370 us; speedup 1.0000x reference)
//
#include <hip/hip_runtime.h>
#include <stdint.h>

#define BB 16
#define TT 1024
#define DD 256
#define NACC 64   // spread accumulator slots (reduces same-address atomic serialization)

typedef __attribute__((ext_vector_type(8))) short short8;
typedef __attribute__((ext_vector_type(4))) float floatx4;
typedef __attribute__((ext_vector_type(4))) float fvec4;   // builtin-compatible float4

// global -> LDS direct copy, 16 B per lane; LDS dest is wave-uniform base + lane*16
#define GLDS16(gp, lp)                                                              \
    __builtin_amdgcn_global_load_lds(                                               \
        (__attribute__((address_space(1))) const void*)(gp),                        \
        (__attribute__((address_space(3))) void*)(lp), 16, 0, 0)

__device__ __forceinline__ unsigned short f2bf(float f) {
    union { float f; unsigned int u; } c; c.f = f;
    unsigned int u = c.u;
    unsigned int r = (u + 0x7FFFu + ((u >> 16) & 1u)) >> 16;
    return (unsigned short)r;
}

// One 64-lane wave per row of z (D=256 -> 4 floats/lane).
// Also zeroes the 64 global double accumulator slots and the ticket.
__global__ __launch_bounds__(256) void prep_kernel(
    const float* __restrict__ z, float* __restrict__ z2,
    unsigned short* __restrict__ zb, double* __restrict__ acc,
    unsigned int* __restrict__ ticket) {
    if (blockIdx.x == 0) {
        if (threadIdx.x < NACC) acc[threadIdx.x] = 0.0;
        if (threadIdx.x == NACC) *ticket = 0u;
    }
    const int lane = threadIdx.x & 63;
    const int row  = blockIdx.x * 4 + (threadIdx.x >> 6);   // [0, BB*TT)
    const float4 v = ((const float4*)(z + (size_t)row * DD))[lane];
    float ss = v.x * v.x + v.y * v.y + v.z * v.z + v.w * v.w;
    ushort4 o;
    o.x = f2bf(v.x); o.y = f2bf(v.y); o.z = f2bf(v.z); o.w = f2bf(v.w);
    ((ushort4*)(zb + (size_t)row * DD))[lane] = o;
#pragma unroll
    for (int off = 32; off > 0; off >>= 1) ss += __shfl_down(ss, off);
    if (lane == 0) z2[row] = ss;
}

// One wave = one 32x32 (t,s) tile.
//  - ALL 16 gt chunk-fetches issued at wave start:
//      half 1 (rows tq+0..1 / tq+16..17) -> VGPRs (nontemporal, 32 VGPR liveness)
//      half 2 (rows tq+2..3 / tq+18..19) -> LDS via global_load_lds (0 VGPR cost)
//    so the memory pipe never drains until the tile is done.
//  - Gram tile via 2x2 mfma_f32_16x16x32_bf16 over D=256 (covers load latency)
//  - finalize fused via atomic ticket: last block reduces the 64 double slots.
// A-frag: lane holds z[t0 + (lane&15)][kstep*32 + (lane>>4)*8 .. +7]
// C/D:    G[t0 + (lane>>4)*4 + r][s0 + (lane&15)]   [m89/m91 layout]
__global__ __launch_bounds__(256) void patch_kernel(
    const unsigned short* __restrict__ zb, const float* __restrict__ z2,
    const float* __restrict__ gt, const float* __restrict__ sigma,
    double* __restrict__ acc, unsigned int* __restrict__ ticket,
    float* __restrict__ out) {
    // 4 waves * 8 chunks * 64 lanes * 16 B = 32 KB exactly -> 5 blocks/CU by LDS
    __shared__ __attribute__((aligned(16))) float lds_gt[4][8][64][4];

    const float LOG2E = 1.4426950408889634f;
    const float s0v = sigma[0], s1v = sigma[1], s2v = sigma[2], s3v = sigma[3];
    const float nc0 = -LOG2E * 0.5f / (s0v * s0v);
    const float nc1 = -LOG2E * 0.5f / (s1v * s1v);
    const float nc2 = -LOG2E * 0.5f / (s2v * s2v);
    const float nc3 = -LOG2E * 0.5f / (s3v * s3v);

    const int tid  = threadIdx.x;
    const int lane = tid & 63;
    const int wv   = tid >> 6;
    const int quad = lane >> 4;
    const int m    = lane & 15;
    const int wid  = blockIdx.x * 4 + wv;   // one 32x32 tile per wave

    const int b   = wid >> 10;
    const int rem = wid & 1023;
    const int t0  = (rem >> 5) << 5;
    const int s0  = (rem & 31) << 5;

    const float* gtb = gt + (size_t)b * TT * TT * 4;
    const int    tq  = t0 + quad * 4;

    // ---- half 1 of gt stream: rows r=0,1 (8 x float4, nontemporal, to VGPR) ----
    fvec4 gtv[8];
#pragma unroll
    for (int r = 0; r < 2; ++r) {
        const size_t row0 = (size_t)(tq + r) * TT;
        const size_t row1 = (size_t)(tq + 16 + r) * TT;
        gtv[r * 4 + 0] = __builtin_nontemporal_load((const fvec4*)(gtb + (row0 + (s0 + m)) * 4));
        gtv[r * 4 + 1] = __builtin_nontemporal_load((const fvec4*)(gtb + (row0 + (s0 + 16 + m)) * 4));
        gtv[r * 4 + 2] = __builtin_nontemporal_load((const fvec4*)(gtb + (row1 + (s0 + m)) * 4));
        gtv[r * 4 + 3] = __builtin_nontemporal_load((const fvec4*)(gtb + (row1 + (s0 + 16 + m)) * 4));
    }

    // ---- half 2 of gt stream issued NOW, direct to LDS (no VGPR, no drain stall) ----
    // lane l's 16 B land at lds_gt[wv][c][l][0..3]; same lane reads them back.
#pragma unroll
    for (int r = 0; r < 2; ++r) {
        const size_t row0 = (size_t)(tq + 2 + r) * TT;
        const size_t row1 = (size_t)(tq + 18 + r) * TT;
        GLDS16(gtb + (row0 + (s0 + m)) * 4,      &lds_gt[wv][r * 4 + 0][0][0]);
        GLDS16(gtb + (row0 + (s0 + 16 + m)) * 4, &lds_gt[wv][r * 4 + 1][0][0]);
        GLDS16(gtb + (row1 + (s0 + m)) * 4,      &lds_gt[wv][r * 4 + 2][0][0]);
        GLDS16(gtb + (row1 + (s0 + 16 + m)) * 4, &lds_gt[wv][r * 4 + 3][0][0]);
    }

    // ---- Gram tile via MFMA (overlaps with the in-flight gt stream) ----
    const unsigned short* zrow = zb + (size_t)b * TT * DD;
    const short8* at0 = (const short8*)(zrow + (t0 + m) * DD + quad * 8);
    const short8* at1 = (const short8*)(zrow + (t0 + 16 + m) * DD + quad * 8);
    const short8* bs0 = (const short8*)(zrow + (s0 + m) * DD + quad * 8);
    const short8* bs1 = (const short8*)(zrow + (s0 + 16 + m) * DD + quad * 8);

    floatx4 g00 = {0.f, 0.f, 0.f, 0.f};
    floatx4 g01 = {0.f, 0.f, 0.f, 0.f};
    floatx4 g10 = {0.f, 0.f, 0.f, 0.f};
    floatx4 g11 = {0.f, 0.f, 0.f, 0.f};
#pragma unroll
    for (int k = 0; k < 8; ++k) {
        const short8 a0 = at0[k * 4];
        const short8 a1 = at1[k * 4];
        const short8 b0 = bs0[k * 4];
        const short8 b1 = bs1[k * 4];
        g00 = __builtin_amdgcn_mfma_f32_16x16x32_bf16(a0, b0, g00, 0, 0, 0);
        g01 = __builtin_amdgcn_mfma_f32_16x16x32_bf16(a0, b1, g01, 0, 0, 0);
        g10 = __builtin_amdgcn_mfma_f32_16x16x32_bf16(a1, b0, g10, 0, 0, 0);
        g11 = __builtin_amdgcn_mfma_f32_16x16x32_bf16(a1, b1, g11, 0, 0, 0);
    }

    const float* z2b  = z2 + b * TT;
    const float  z2s0 = z2b[s0 + m];
    const float  z2s1 = z2b[s0 + 16 + m];

    float partial = 0.f;

    // ---- epilogue half 1: consume VGPR-staged chunks ----
#pragma unroll
    for (int r = 0; r < 2; ++r) {
        const float z2t0 = z2b[tq + r];
        const float z2t1 = z2b[tq + 16 + r];
        const float e00 = z2t0 + z2s0, e01 = z2t0 + z2s1;
        const float e10 = z2t1 + z2s0, e11 = z2t1 + z2s1;
        {
            const fvec4 d = gtv[r * 4 + 0];
            const float k2 = fmaf(nc3, d.w * d.w, fmaf(nc2, d.z * d.z,
                             fmaf(nc1, d.y * d.y, nc0 * d.x * d.x)));
            partial = fmaf(exp2f(k2), fmaf(-2.f, g00[r], e00), partial);
        }
        {
            const fvec4 d = gtv[r * 4 + 1];
            const float k2 = fmaf(nc3, d.w * d.w, fmaf(nc2, d.z * d.z,
                             fmaf(nc1, d.y * d.y, nc0 * d.x * d.x)));
            partial = fmaf(exp2f(k2), fmaf(-2.f, g01[r], e01), partial);
        }
        {
            const fvec4 d = gtv[r * 4 + 2];
            const float k2 = fmaf(nc3, d.w * d.w, fmaf(nc2, d.z * d.z,
                             fmaf(nc1, d.y * d.y, nc0 * d.x * d.x)));
            partial = fmaf(exp2f(k2), fmaf(-2.f, g10[r], e10), partial);
        }
        {
            const fvec4 d = gtv[r * 4 + 3];
            const float k2 = fmaf(nc3, d.w * d.w, fmaf(nc2, d.z * d.z,
                             fmaf(nc1, d.y * d.y, nc0 * d.x * d.x)));
            partial = fmaf(exp2f(k2), fmaf(-2.f, g11[r], e11), partial);
        }
    }

    // ---- epilogue half 2: consume LDS-staged chunks (loads were issued at t0) ----
    asm volatile("s_waitcnt vmcnt(0)" ::: "memory");
#pragma unroll
    for (int r = 0; r < 2; ++r) {
        const int rr = 2 + r;
        const float z2t0 = z2b[tq + rr];
        const float z2t1 = z2b[tq + 16 + rr];
        const float e00 = z2t0 + z2s0, e01 = z2t0 + z2s1;
        const float e10 = z2t1 + z2s0, e11 = z2t1 + z2s1;
        const fvec4 d0 = *(const fvec4*)&lds_gt[wv][r * 4 + 0][lane][0];
        const fvec4 d1 = *(const fvec4*)&lds_gt[wv][r * 4 + 1][lane][0];
        const fvec4 d2 = *(const fvec4*)&lds_gt[wv][r * 4 + 2][lane][0];
        const fvec4 d3 = *(const fvec4*)&lds_gt[wv][r * 4 + 3][lane][0];
        {
            const float k2 = fmaf(nc3, d0.w * d0.w, fmaf(nc2, d0.z * d0.z,
                             fmaf(nc1, d0.y * d0.y, nc0 * d0.x * d0.x)));
            partial = fmaf(exp2f(k2), fmaf(-2.f, g00[rr], e00), partial);
        }
        {
            const float k2 = fmaf(nc3, d1.w * d1.w, fmaf(nc2, d1.z * d1.z,
                             fmaf(nc1, d1.y * d1.y, nc0 * d1.x * d1.x)));
            partial = fmaf(exp2f(k2), fmaf(-2.f, g01[rr], e01), partial);
        }
        {
            const float k2 = fmaf(nc3, d2.w * d2.w, fmaf(nc2, d2.z * d2.z,
                             fmaf(nc1, d2.y * d2.y, nc0 * d2.x * d2.x)));
            partial = fmaf(exp2f(k2), fmaf(-2.f, g10[rr], e10), partial);
        }
        {
            const float k2 = fmaf(nc3, d3.w * d3.w, fmaf(nc2, d3.z * d3.z,
                             fmaf(nc1, d3.y * d3.y, nc0 * d3.x * d3.x)));
            partial = fmaf(exp2f(k2), fmaf(-2.f, g11[rr], e11), partial);
        }
    }

    // ---- wave reduce, per-wave double atomic into a spread slot ----
#pragma unroll
    for (int off = 32; off > 0; off >>= 1) partial += __shfl_down(partial, off);
    if (lane == 0) atomicAdd(&acc[wid & (NACC - 1)], (double)partial);

    // ---- fused finalize: last block (by ticket) reduces the 64 slots ----
    // __syncthreads drains each wave's vmcnt -> all 4 atomics completed at the
    // coherence point before the ticket is taken.
    __syncthreads();
    if (wv == 0) {
        unsigned int t = 0;
        if (lane == 0) {
            __threadfence();
            t = atomicAdd(ticket, 1u);
        }
        t = __shfl(t, 0);
        if (t == gridDim.x - 1) {
            __threadfence();
            double v = __hip_atomic_load(&acc[lane], __ATOMIC_RELAXED,
                                         __HIP_MEMORY_SCOPE_AGENT);
#pragma unroll
            for (int off = 32; off > 0; off >>= 1) v += __shfl_down(v, off);
            if (lane == 0)
                out[0] = (float)(v * (1.0 / ((double)BB * (double)TT * (double)TT)));
        }
    }
}

extern "C" void kernel_launch(void* const* d_in, const int* in_sizes, int n_in,
                              void* d_out, int out_size, void* d_ws, size_t ws_size,
                              hipStream_t stream) {
    const float* z     = (const float*)d_in[0];   // [16,1024,256]
    const float* gt    = (const float*)d_in[1];   // [16,1024,1024,4]
    const float* sigma = (const float*)d_in[2];   // [4]
    float* out = (float*)d_out;

    // ws: [0,512)=64 double acc slots | [512,516)=ticket | 1024: z2 (64 KB)
    //     | 66560: zb (8 MB bf16)
    char* ws = (char*)d_ws;
    double* acc          = (double*)ws;
    unsigned int* ticket = (unsigned int*)(ws + 512);
    float* z2            = (float*)(ws + 1024);
    unsigned short* zb   = (unsigned short*)(ws + 1024 + (size_t)BB * TT * sizeof(float));

    prep_kernel<<<BB * TT / 4, 256, 0, stream>>>(z, z2, zb, acc, ticket);
    patch_kernel<<<BB * (TT / 32) * (TT / 32) / 4, 256, 0, stream>>>(
        zb, z2, gt, sigma, acc, ticket, out);
}

// Round 8
// 388.241 us; speedup vs baseline: 1.4820x; 1.4820x over previous
//
#include <hip/hip_runtime.h>
#include <stdint.h>

#define BB 16
#define TT 1024
#define DD 256
#define NACC 64   // spread accumulator slots (reduces same-address atomic serialization)

typedef __attribute__((ext_vector_type(8))) short short8;
typedef __attribute__((ext_vector_type(4))) float floatx4;
typedef __attribute__((ext_vector_type(4))) float fvec4;   // builtin-compatible float4

// global -> LDS direct copy, 16 B per lane; LDS dest is wave-uniform base + lane*16
#define GLDS16(gp, lp)                                                              \
    __builtin_amdgcn_global_load_lds(                                               \
        (__attribute__((address_space(1))) const void*)(gp),                        \
        (__attribute__((address_space(3))) void*)(lp), 16, 0, 0)

__device__ __forceinline__ unsigned short f2bf(float f) {
    union { float f; unsigned int u; } c; c.f = f;
    unsigned int u = c.u;
    unsigned int r = (u + 0x7FFFu + ((u >> 16) & 1u)) >> 16;
    return (unsigned short)r;
}

// One 64-lane wave per row of z (D=256 -> 4 floats/lane).
// Also zeroes the 64 global double accumulator slots.
__global__ __launch_bounds__(256) void prep_kernel(
    const float* __restrict__ z, float* __restrict__ z2,
    unsigned short* __restrict__ zb, double* __restrict__ acc) {
    if (blockIdx.x == 0 && threadIdx.x < NACC) acc[threadIdx.x] = 0.0;
    const int lane = threadIdx.x & 63;
    const int row  = blockIdx.x * 4 + (threadIdx.x >> 6);   // [0, BB*TT)
    const float4 v = ((const float4*)(z + (size_t)row * DD))[lane];
    float ss = v.x * v.x + v.y * v.y + v.z * v.z + v.w * v.w;
    ushort4 o;
    o.x = f2bf(v.x); o.y = f2bf(v.y); o.z = f2bf(v.z); o.w = f2bf(v.w);
    ((ushort4*)(zb + (size_t)row * DD))[lane] = o;
#pragma unroll
    for (int off = 32; off > 0; off >>= 1) ss += __shfl_down(ss, off);
    if (lane == 0) z2[row] = ss;
}

// One wave = one 32x32 (t,s) tile.
//  - ALL 16 gt chunk-fetches issued at wave start:
//      half 1 (rows tq+0..1 / tq+16..17) -> VGPRs (nontemporal, 32 VGPR liveness)
//      half 2 (rows tq+2..3 / tq+18..19) -> LDS via global_load_lds (0 VGPR cost)
//    so the memory pipe never drains until the tile is done.
//  - Gram tile via 2x2 mfma_f32_16x16x32_bf16 over D=256 (covers load latency)
//  - reduction: wave shfl -> shared red[4] -> ONE double atomic per block
//    (Round-7 post-mortem: per-wave atomics + barrier-waiting on their ACKs
//     serialized the whole grid at the coherence point -> 287 us stall.)
// A-frag: lane holds z[t0 + (lane&15)][kstep*32 + (lane>>4)*8 .. +7]
// C/D:    G[t0 + (lane>>4)*4 + r][s0 + (lane&15)]   [m89/m91 layout]
__global__ __launch_bounds__(256) void patch_kernel(
    const unsigned short* __restrict__ zb, const float* __restrict__ z2,
    const float* __restrict__ gt, const float* __restrict__ sigma,
    double* __restrict__ acc) {
    // 4 waves * 8 chunks * 64 lanes * 16 B = 32 KB -> 5 blocks/CU by LDS
    __shared__ __attribute__((aligned(16))) float lds_gt[4][8][64][4];

    const float LOG2E = 1.4426950408889634f;
    const float s0v = sigma[0], s1v = sigma[1], s2v = sigma[2], s3v = sigma[3];
    const float nc0 = -LOG2E * 0.5f / (s0v * s0v);
    const float nc1 = -LOG2E * 0.5f / (s1v * s1v);
    const float nc2 = -LOG2E * 0.5f / (s2v * s2v);
    const float nc3 = -LOG2E * 0.5f / (s3v * s3v);

    const int tid  = threadIdx.x;
    const int lane = tid & 63;
    const int wv   = tid >> 6;
    const int quad = lane >> 4;
    const int m    = lane & 15;
    const int wid  = blockIdx.x * 4 + wv;   // one 32x32 tile per wave

    const int b   = wid >> 10;
    const int rem = wid & 1023;
    const int t0  = (rem >> 5) << 5;
    const int s0  = (rem & 31) << 5;

    const float* gtb = gt + (size_t)b * TT * TT * 4;
    const int    tq  = t0 + quad * 4;

    // ---- half 1 of gt stream: rows r=0,1 (8 x float4, nontemporal, to VGPR) ----
    fvec4 gtv[8];
#pragma unroll
    for (int r = 0; r < 2; ++r) {
        const size_t row0 = (size_t)(tq + r) * TT;
        const size_t row1 = (size_t)(tq + 16 + r) * TT;
        gtv[r * 4 + 0] = __builtin_nontemporal_load((const fvec4*)(gtb + (row0 + (s0 + m)) * 4));
        gtv[r * 4 + 1] = __builtin_nontemporal_load((const fvec4*)(gtb + (row0 + (s0 + 16 + m)) * 4));
        gtv[r * 4 + 2] = __builtin_nontemporal_load((const fvec4*)(gtb + (row1 + (s0 + m)) * 4));
        gtv[r * 4 + 3] = __builtin_nontemporal_load((const fvec4*)(gtb + (row1 + (s0 + 16 + m)) * 4));
    }

    // ---- half 2 of gt stream issued NOW, direct to LDS (no VGPR, no drain stall) ----
    // lane l's 16 B land at lds_gt[wv][c][l][0..3]; same lane reads them back.
#pragma unroll
    for (int r = 0; r < 2; ++r) {
        const size_t row0 = (size_t)(tq + 2 + r) * TT;
        const size_t row1 = (size_t)(tq + 18 + r) * TT;
        GLDS16(gtb + (row0 + (s0 + m)) * 4,      &lds_gt[wv][r * 4 + 0][0][0]);
        GLDS16(gtb + (row0 + (s0 + 16 + m)) * 4, &lds_gt[wv][r * 4 + 1][0][0]);
        GLDS16(gtb + (row1 + (s0 + m)) * 4,      &lds_gt[wv][r * 4 + 2][0][0]);
        GLDS16(gtb + (row1 + (s0 + 16 + m)) * 4, &lds_gt[wv][r * 4 + 3][0][0]);
    }

    // ---- Gram tile via MFMA (overlaps with the in-flight gt stream) ----
    const unsigned short* zrow = zb + (size_t)b * TT * DD;
    const short8* at0 = (const short8*)(zrow + (t0 + m) * DD + quad * 8);
    const short8* at1 = (const short8*)(zrow + (t0 + 16 + m) * DD + quad * 8);
    const short8* bs0 = (const short8*)(zrow + (s0 + m) * DD + quad * 8);
    const short8* bs1 = (const short8*)(zrow + (s0 + 16 + m) * DD + quad * 8);

    floatx4 g00 = {0.f, 0.f, 0.f, 0.f};
    floatx4 g01 = {0.f, 0.f, 0.f, 0.f};
    floatx4 g10 = {0.f, 0.f, 0.f, 0.f};
    floatx4 g11 = {0.f, 0.f, 0.f, 0.f};
#pragma unroll
    for (int k = 0; k < 8; ++k) {
        const short8 a0 = at0[k * 4];
        const short8 a1 = at1[k * 4];
        const short8 b0 = bs0[k * 4];
        const short8 b1 = bs1[k * 4];
        g00 = __builtin_amdgcn_mfma_f32_16x16x32_bf16(a0, b0, g00, 0, 0, 0);
        g01 = __builtin_amdgcn_mfma_f32_16x16x32_bf16(a0, b1, g01, 0, 0, 0);
        g10 = __builtin_amdgcn_mfma_f32_16x16x32_bf16(a1, b0, g10, 0, 0, 0);
        g11 = __builtin_amdgcn_mfma_f32_16x16x32_bf16(a1, b1, g11, 0, 0, 0);
    }

    const float* z2b  = z2 + b * TT;
    const float  z2s0 = z2b[s0 + m];
    const float  z2s1 = z2b[s0 + 16 + m];

    float partial = 0.f;

    // ---- epilogue half 1: consume VGPR-staged chunks ----
#pragma unroll
    for (int r = 0; r < 2; ++r) {
        const float z2t0 = z2b[tq + r];
        const float z2t1 = z2b[tq + 16 + r];
        const float e00 = z2t0 + z2s0, e01 = z2t0 + z2s1;
        const float e10 = z2t1 + z2s0, e11 = z2t1 + z2s1;
        {
            const fvec4 d = gtv[r * 4 + 0];
            const float k2 = fmaf(nc3, d.w * d.w, fmaf(nc2, d.z * d.z,
                             fmaf(nc1, d.y * d.y, nc0 * d.x * d.x)));
            partial = fmaf(exp2f(k2), fmaf(-2.f, g00[r], e00), partial);
        }
        {
            const fvec4 d = gtv[r * 4 + 1];
            const float k2 = fmaf(nc3, d.w * d.w, fmaf(nc2, d.z * d.z,
                             fmaf(nc1, d.y * d.y, nc0 * d.x * d.x)));
            partial = fmaf(exp2f(k2), fmaf(-2.f, g01[r], e01), partial);
        }
        {
            const fvec4 d = gtv[r * 4 + 2];
            const float k2 = fmaf(nc3, d.w * d.w, fmaf(nc2, d.z * d.z,
                             fmaf(nc1, d.y * d.y, nc0 * d.x * d.x)));
            partial = fmaf(exp2f(k2), fmaf(-2.f, g10[r], e10), partial);
        }
        {
            const fvec4 d = gtv[r * 4 + 3];
            const float k2 = fmaf(nc3, d.w * d.w, fmaf(nc2, d.z * d.z,
                             fmaf(nc1, d.y * d.y, nc0 * d.x * d.x)));
            partial = fmaf(exp2f(k2), fmaf(-2.f, g11[r], e11), partial);
        }
    }

    // ---- epilogue half 2: consume LDS-staged chunks (loads were issued at t0) ----
    asm volatile("s_waitcnt vmcnt(0)" ::: "memory");
#pragma unroll
    for (int r = 0; r < 2; ++r) {
        const int rr = 2 + r;
        const float z2t0 = z2b[tq + rr];
        const float z2t1 = z2b[tq + 16 + rr];
        const float e00 = z2t0 + z2s0, e01 = z2t0 + z2s1;
        const float e10 = z2t1 + z2s0, e11 = z2t1 + z2s1;
        const fvec4 d0 = *(const fvec4*)&lds_gt[wv][r * 4 + 0][lane][0];
        const fvec4 d1 = *(const fvec4*)&lds_gt[wv][r * 4 + 1][lane][0];
        const fvec4 d2 = *(const fvec4*)&lds_gt[wv][r * 4 + 2][lane][0];
        const fvec4 d3 = *(const fvec4*)&lds_gt[wv][r * 4 + 3][lane][0];
        {
            const float k2 = fmaf(nc3, d0.w * d0.w, fmaf(nc2, d0.z * d0.z,
                             fmaf(nc1, d0.y * d0.y, nc0 * d0.x * d0.x)));
            partial = fmaf(exp2f(k2), fmaf(-2.f, g00[rr], e00), partial);
        }
        {
            const float k2 = fmaf(nc3, d1.w * d1.w, fmaf(nc2, d1.z * d1.z,
                             fmaf(nc1, d1.y * d1.y, nc0 * d1.x * d1.x)));
            partial = fmaf(exp2f(k2), fmaf(-2.f, g01[rr], e01), partial);
        }
        {
            const float k2 = fmaf(nc3, d2.w * d2.w, fmaf(nc2, d2.z * d2.z,
                             fmaf(nc1, d2.y * d2.y, nc0 * d2.x * d2.x)));
            partial = fmaf(exp2f(k2), fmaf(-2.f, g10[rr], e10), partial);
        }
        {
            const float k2 = fmaf(nc3, d3.w * d3.w, fmaf(nc2, d3.z * d3.z,
                             fmaf(nc1, d3.y * d3.y, nc0 * d3.x * d3.x)));
            partial = fmaf(exp2f(k2), fmaf(-2.f, g11[rr], e11), partial);
        }
    }

    // wave reduce, block reduce, one double atomic per block into a spread slot
#pragma unroll
    for (int off = 32; off > 0; off >>= 1) partial += __shfl_down(partial, off);
    __shared__ float red[4];
    if (lane == 0) red[wv] = partial;
    __syncthreads();
    if (tid == 0)
        atomicAdd(&acc[blockIdx.x & (NACC - 1)],
                  (double)(red[0] + red[1] + red[2] + red[3]));
}

__global__ void finalize_kernel(const double* __restrict__ acc, float* __restrict__ out) {
    double v = acc[threadIdx.x];   // 64 threads = 1 wave
#pragma unroll
    for (int off = 32; off > 0; off >>= 1) v += __shfl_down(v, off);
    if (threadIdx.x == 0)
        out[0] = (float)(v * (1.0 / ((double)BB * (double)TT * (double)TT)));
}

extern "C" void kernel_launch(void* const* d_in, const int* in_sizes, int n_in,
                              void* d_out, int out_size, void* d_ws, size_t ws_size,
                              hipStream_t stream) {
    const float* z     = (const float*)d_in[0];   // [16,1024,256]
    const float* gt    = (const float*)d_in[1];   // [16,1024,1024,4]
    const float* sigma = (const float*)d_in[2];   // [4]
    float* out = (float*)d_out;

    // ws: [0,512)=64 double acc slots | 1024: z2 (64 KB) | 66560: zb (8 MB bf16)
    char* ws = (char*)d_ws;
    double* acc        = (double*)ws;
    float* z2          = (float*)(ws + 1024);
    unsigned short* zb = (unsigned short*)(ws + 1024 + (size_t)BB * TT * sizeof(float));

    prep_kernel<<<BB * TT / 4, 256, 0, stream>>>(z, z2, zb, acc);
    patch_kernel<<<BB * (TT / 32) * (TT / 32) / 4, 256, 0, stream>>>(zb, z2, gt, sigma, acc);
    finalize_kernel<<<1, 64, 0, stream>>>(acc, out);
}